// Round 1
// 401.395 us; speedup vs baseline: 1.1269x; 1.1269x over previous
//
#include <hip/hip_runtime.h>

#define KNN 3
#define EPS 1e-8f
#define B_BATCH 4
#define QPB 16   // queries per block = 4 waves x 4 queries/wave

// ---------------------------------------------------------------------------
// Fused kNN over all 4 stages. Wave-per-4-queries; whole xyz2[b] staged in
// LDS SoA (lane-consecutive reads -> 2-way aliasing = free). Each lane scans
// n2/64 candidates for 4 queries simultaneously (shared LDS reads, 4
// independent branchless top-3 insert chains on packed u64 keys
// dist_bits<<32|idx; dist>=0 so float bit order == value order; low-word idx
// tie-breaks to smaller j like jax top_k). 6-step __shfl_xor butterfly with a
// 6-op merge network (lowest-3 of two sorted-3 lists). Lane 0 writes a packed
// record int4{j0,j1,j2,bits(w0n)} + w1n; consumer reconstructs w2n=1-w0n-w1n.
// ---------------------------------------------------------------------------
__device__ __forceinline__ unsigned long long u64min(unsigned long long a,
                                                     unsigned long long b) {
    return a < b ? a : b;
}
__device__ __forceinline__ unsigned long long u64max(unsigned long long a,
                                                     unsigned long long b) {
    return a > b ? a : b;
}

struct KnnAll {
    const float* xq[4];
    const float* xs[4];
    int4*  rec[4];    // (B, n1): {j0, j1, j2, float_bits(w0n)}
    float* w1[4];     // (B, n1): w1n
    int n1[4], n2[4], blk0[4];
};

__global__ __launch_bounds__(256) void knn_all_kernel(KnnAll P)
{
    __shared__ float s_x[2048], s_y[2048], s_z[2048];
    const int b  = blockIdx.y;
    const int bx = blockIdx.x;

    // slot selection with CONSTANT struct indices only (runtime-indexed
    // kernarg arrays can spill to scratch -- rule #20)
    const float* xq; const float* xs; int4* orec; float* ow1;
    int n1, n2, bs;
    if (bx >= P.blk0[3]) {
        xq=P.xq[3]; xs=P.xs[3]; orec=P.rec[3]; ow1=P.w1[3];
        n1=P.n1[3]; n2=P.n2[3]; bs=bx-P.blk0[3];
    } else if (bx >= P.blk0[2]) {
        xq=P.xq[2]; xs=P.xs[2]; orec=P.rec[2]; ow1=P.w1[2];
        n1=P.n1[2]; n2=P.n2[2]; bs=bx-P.blk0[2];
    } else if (bx >= P.blk0[1]) {
        xq=P.xq[1]; xs=P.xs[1]; orec=P.rec[1]; ow1=P.w1[1];
        n1=P.n1[1]; n2=P.n2[1]; bs=bx-P.blk0[1];
    } else {
        xq=P.xq[0]; xs=P.xs[0]; orec=P.rec[0]; ow1=P.w1[0];
        n1=P.n1[0]; n2=P.n2[0]; bs=bx;
    }

    const float* src2 = xs + (size_t)b * n2 * 3;
    for (int i = threadIdx.x; i < n2; i += blockDim.x) {
        s_x[i] = src2[i * 3 + 0];
        s_y[i] = src2[i * 3 + 1];
        s_z[i] = src2[i * 3 + 2];
    }
    __syncthreads();

    const int lane = threadIdx.x & 63;
    const int wave = threadIdx.x >> 6;
    const int q0 = bs * QPB + wave * 4;

    float qx[4], qy[4], qz[4];
#pragma unroll
    for (int r = 0; r < 4; ++r) {
        const float* p = xq + ((size_t)b * n1 + q0 + r) * 3;
        qx[r] = p[0]; qy[r] = p[1]; qz[r] = p[2];
    }

    unsigned long long k0[4], k1[4], k2[4];
#pragma unroll
    for (int r = 0; r < 4; ++r) { k0[r] = ~0ull; k1[r] = ~0ull; k2[r] = ~0ull; }

    for (int j = lane; j < n2; j += 64) {
        const float sx = s_x[j], sy = s_y[j], sz = s_z[j];
#pragma unroll
        for (int r = 0; r < 4; ++r) {
            const float dx = qx[r] - sx;
            const float dy = qy[r] - sy;
            const float dz = qz[r] - sz;
            const float d = fmaf(dz, dz, fmaf(dy, dy, dx * dx));
            const unsigned long long key =
                ((unsigned long long)__float_as_uint(d) << 32) | (unsigned)j;
            const unsigned long long u = u64max(key, k0[r]);
            k0[r] = u64min(key, k0[r]);
            const unsigned long long v = u64max(u, k1[r]);
            k1[r] = u64min(u, k1[r]);
            k2[r] = u64min(v, k2[r]);
        }
    }

#pragma unroll
    for (int r = 0; r < 4; ++r) {
        // butterfly merge: both partners compute the same lowest-3 of the
        // two sorted triples (6-op symmetric network), so all lanes converge.
#pragma unroll
        for (int m = 1; m < 64; m <<= 1) {
            const unsigned long long b0 = __shfl_xor(k0[r], m, 64);
            const unsigned long long b1 = __shfl_xor(k1[r], m, 64);
            const unsigned long long b2 = __shfl_xor(k2[r], m, 64);
            const unsigned long long c0 = u64min(k0[r], b0);
            const unsigned long long mm = u64max(k0[r], b0);
            const unsigned long long nn = u64min(k1[r], b1);
            const unsigned long long c1 = u64min(mm, nn);
            const unsigned long long c2 =
                u64min(u64max(mm, nn), u64min(k2[r], b2));
            k0[r] = c0; k1[r] = c1; k2[r] = c2;
        }
        if (lane == 0) {
            const float d0 = __uint_as_float((unsigned)(k0[r] >> 32));
            const float d1 = __uint_as_float((unsigned)(k1[r] >> 32));
            const float d2 = __uint_as_float((unsigned)(k2[r] >> 32));
            float w0 = 1.0f / (d0 + EPS);
            float w1 = 1.0f / (d1 + EPS);
            float w2 = 1.0f / (d2 + EPS);
            const float inv = 1.0f / (w0 + w1 + w2);
            const size_t o = (size_t)b * n1 + q0 + r;
            int4 rec;
            rec.x = (int)(unsigned)(k0[r] & 0xFFFFFFFFu);
            rec.y = (int)(unsigned)(k1[r] & 0xFFFFFFFFu);
            rec.z = (int)(unsigned)(k2[r] & 0xFFFFFFFFu);
            rec.w = __float_as_int(w0 * inv);
            orec[o] = rec;
            ow1[o]  = w1 * inv;
        }
    }
}

// ---------------------------------------------------------------------------
// Fused copy + interp per stage.
//   blockIdx.x < c1/CH : copy p1 rows -> out[0, c1)   (float4 block copy)
//   else               : interp into out[c1, c1+c2)
// Interp stages a TRANSPOSED tile s[j][CH] (CH=4) so each neighbor gather is
// ONE ds_read_b128 (4 channels) instead of 4 conflicted ds_read_b32; staging
// writes are linear (conflict-free). Per query: 2 global loads (int4 rec +
// w1), 3 b128 LDS reads, 12 FMA, 4 coalesced stores.
// ---------------------------------------------------------------------------
template <int CH>
__global__ __launch_bounds__(256) void stage_kernel(
    const float* __restrict__ p1,      // (B, c1, n1) skip features
    const float* __restrict__ p2,      // (B, c2, n2) deep features
    const int4*  __restrict__ rec,     // (B, n1) packed knn record
    const float* __restrict__ w1a,     // (B, n1) w1n
    float* __restrict__ out,           // (B, c1+c2, n1)
    int n1, int n2, int c1, int c2)
{
    extern __shared__ __align__(16) float s[];   // CH * n2 floats, s[j*CH+c]
    const int b = blockIdx.y;
    const int c_out = c1 + c2;
    const int nCopy = c1 / CH;

    if ((int)blockIdx.x < nCopy) {
        const float4* src = (const float4*)(p1 + ((size_t)b * c1 + blockIdx.x * CH) * n1);
        float4*       dst = (float4*)(out + ((size_t)b * c_out + blockIdx.x * CH) * n1);
        const int n4 = CH * n1 / 4;
        for (int i = threadIdx.x; i < n4; i += 256)
            dst[i] = src[i];
        return;
    }

    const int c0 = ((int)blockIdx.x - nCopy) * CH;
    const float* srcp = p2 + ((size_t)b * c2 + c0) * n2;
    // transposed staging: s[j*CH + c] = p2[c0+c][j]; LDS writes linear in i
    // -> conflict-free; global reads hit 4 rows x 64B segments per wave.
    for (int i = threadIdx.x; i < CH * n2; i += 256) {
        const int c = i % CH;
        const int j = i / CH;
        s[i] = srcp[(size_t)c * n2 + j];
    }
    __syncthreads();

    const int4*  recb = rec + (size_t)b * n1;
    const float* w1b  = w1a + (size_t)b * n1;
    float* outb = out + ((size_t)b * c_out + c1 + c0) * n1;

    for (int q = threadIdx.x; q < n1; q += 256) {
        const int4 r  = recb[q];
        const float w0 = __int_as_float(r.w);
        const float w1 = w1b[q];
        const float w2 = 1.0f - w0 - w1;
        const float4 v0 = *(const float4*)(s + r.x * CH);
        const float4 v1 = *(const float4*)(s + r.y * CH);
        const float4 v2 = *(const float4*)(s + r.z * CH);
        outb[(size_t)0 * n1 + q] = w0 * v0.x + w1 * v1.x + w2 * v2.x;
        outb[(size_t)1 * n1 + q] = w0 * v0.y + w1 * v1.y + w2 * v2.y;
        outb[(size_t)2 * n1 + q] = w0 * v0.z + w1 * v1.z + w2 * v2.z;
        outb[(size_t)3 * n1 + q] = w0 * v0.w + w1 * v1.w + w2 * v2.w;
    }
}

// ---------------------------------------------------------------------------
extern "C" void kernel_launch(void* const* d_in, const int* in_sizes, int n_in,
                              void* d_out, int out_size, void* d_ws, size_t ws_size,
                              hipStream_t stream)
{
    // setup_inputs order: xyz0, x0, xyz1, x1, xyz2, x2, xyz3, x3, xyz4, x4
    const float* xyz[5];
    const float* xf[5];
    for (int i = 0; i < 5; ++i) {
        xyz[i] = (const float*)d_in[2 * i];
        xf[i]  = (const float*)d_in[2 * i + 1];
    }

    float* ws = (float*)d_ws;
    float* interm0 = ws;                                   // (4,1536,128)
    float* interm1 = interm0 + (size_t)4 * 1536 * 128;     // (4,1792,512)
    float* interm2 = interm1 + (size_t)4 * 1792 * 512;     // (4,1920,2048)
    char*  kb = (char*)(interm2 + (size_t)4 * 1920 * 2048); // 16B-aligned

    const int n1s[4] = {128, 512, 2048, 8192};  // exec-stage order
    int4*  rec[4];
    float* w1[4];
    for (int s = 0; s < 4; ++s) { rec[s] = (int4*)kb;  kb += (size_t)B_BATCH * n1s[s] * sizeof(int4); }
    for (int s = 0; s < 4; ++s) { w1[s]  = (float*)kb; kb += (size_t)B_BATCH * n1s[s] * sizeof(float); }

    // --- 1 fused kNN launch; depends only on xyz inputs. Heaviest stage's
    // blocks first (longest-job-first across the 680-block grid).
    KnnAll P;
    P.xq[0]=xyz[0]; P.xs[0]=xyz[1]; P.rec[0]=rec[3]; P.w1[0]=w1[3]; P.n1[0]=8192; P.n2[0]=2048; P.blk0[0]=0;
    P.xq[1]=xyz[1]; P.xs[1]=xyz[2]; P.rec[1]=rec[2]; P.w1[1]=w1[2]; P.n1[1]=2048; P.n2[1]=512;  P.blk0[1]=512;
    P.xq[2]=xyz[2]; P.xs[2]=xyz[3]; P.rec[2]=rec[1]; P.w1[2]=w1[1]; P.n1[2]=512;  P.n2[2]=128;  P.blk0[2]=640;
    P.xq[3]=xyz[3]; P.xs[3]=xyz[4]; P.rec[3]=rec[0]; P.w1[3]=w1[0]; P.n1[3]=128;  P.n2[3]=32;   P.blk0[3]=672;
    {
        dim3 grid(680, B_BATCH);
        knn_all_kernel<<<grid, 256, 0, stream>>>(P);
    }

    struct Stage {
        const float* p1; const float* p2;
        int4* rc; float* ww; float* out;
        int n1, n2, c1, c2;
    };
    const Stage st[4] = {
        { xf[3], xf[4],   rec[0], w1[0], interm0,       128,   32,  512, 1024 },
        { xf[2], interm0, rec[1], w1[1], interm1,       512,  128,  256, 1536 },
        { xf[1], interm1, rec[2], w1[2], interm2,      2048,  512,  128, 1792 },
        { xf[0], interm2, rec[3], w1[3], (float*)d_out, 8192, 2048,  64, 1920 },
    };

    constexpr int CH = 4;
    for (int s = 0; s < 4; ++s) {
        const Stage& S = st[s];
        dim3 grid((S.c1 + S.c2) / CH, B_BATCH);
        const size_t lds = (size_t)CH * S.n2 * sizeof(float);
        stage_kernel<CH><<<grid, 256, lds, stream>>>(
            S.p1, S.p2, S.rc, S.ww, S.out, S.n1, S.n2, S.c1, S.c2);
    }
}